// Round 7
// baseline (381.583 us; speedup 1.0000x reference)
//
#include <hip/hip_runtime.h>
#include <hip/hip_cooperative_groups.h>
#include <math.h>

namespace cg = cooperative_groups;

#define NN   65536
#define BB   256
#define NPGC 256
#define EE   1048576
#define DD   128
#define KK   128
#define NT2  32768
#define OUTD 12
#define BN_EPS 1e-5f
#define INV_N1 (1.f / 65536.f)
#define INV_N2 (1.f / 32768.f)

typedef __attribute__((ext_vector_type(8))) short bf16x8;
typedef __attribute__((ext_vector_type(4))) float f32x4;

__device__ __forceinline__ unsigned short bf16_rne(float v) {
    unsigned u = __float_as_uint(v);
    unsigned r = u + 0x7FFFu + ((u >> 16) & 1u);
    return (unsigned short)(r >> 16);
}

// ---------------- W prep: transpose + split f32 -> bf16 hi/lo, [layer][n][k] ----------------
__global__ void k_prepw(const float* __restrict__ Wg, unsigned short* __restrict__ wtHi,
                        unsigned short* __restrict__ wtLo) {
    int b = blockIdx.x;            // 0..639
    int l = b >> 7, n = b & 127;
    int k = threadIdx.x;           // 128
    float v = Wg[l * 16384 + k * 128 + n];
    unsigned short hb = bf16_rne(v);
    float hf = __uint_as_float((unsigned)hb << 16);
    unsigned short lb = bf16_rne(v - hf);
    wtHi[l * 16384 + n * 128 + k] = hb;
    wtLo[l * 16384 + n * 128 + k] = lb;
}

// ---------------- One GIN layer: gather (LDS h) -> zg staging (global, packed bf16 hi|lo)
//                  -> MFMA vs staged W -> BN stats -> grid sync -> BN+ReLU -> h (LDS) ----------
template<int NODES>   // 256 (phase 1) or 128 (phase 2)
__device__ __forceinline__ void gin_layer(
    int t, unsigned* __restrict__ zgG, float* hF,
    unsigned short (*wS)[4096], const int* offl, const unsigned char* csr8,
    const unsigned short* __restrict__ WH, const unsigned short* __restrict__ WL,
    const float* __restrict__ bgL, const float* __restrict__ gamL,
    const float* __restrict__ betL, float epsL,
    float* __restrict__ bnstL, float invRows, float* scsh,
    cg::grid_group& grid)
{
    const int wv = t >> 6, l = t & 63;
    const int la = l & 15, kg = l >> 4;
    const float2* hF2 = (const float2*)hF;
    const float opEps = 1.f + epsL;
    constexpr int NPW = NODES / 16;   // nodes gathered per wave
    constexpr int AW  = NODES / 16;   // active MFMA waves (16 rows each)

    // ---- gather + pack(bf16 hi|lo) + immediate store to zg (2 live regs per node) ----
    for (int i = 0; i < NPW; ++i) {
        int node = wv * NPW + i;
        int st = offl[node], en = offl[node + 1];
        float2 a = hF2[node * 64 + l];
        float ax = a.x * opEps, ay = a.y * opEps;
        int j = st;
        for (; j + 3 < en; j += 4) {
            int n0 = csr8[j], n1 = csr8[j + 1], n2 = csr8[j + 2], n3 = csr8[j + 3];
            float2 v0 = hF2[n0 * 64 + l];
            float2 v1 = hF2[n1 * 64 + l];
            float2 v2 = hF2[n2 * 64 + l];
            float2 v3 = hF2[n3 * 64 + l];
            ax += v0.x + v1.x + v2.x + v3.x;
            ay += v0.y + v1.y + v2.y + v3.y;
        }
        for (; j < en; ++j) {
            float2 v = hF2[csr8[j] * 64 + l];
            ax += v.x; ay += v.y;
        }
        unsigned hx = bf16_rne(ax);
        unsigned lx = bf16_rne(ax - __uint_as_float(hx << 16));
        unsigned hy = bf16_rne(ay);
        unsigned ly = bf16_rne(ay - __uint_as_float(hy << 16));
        uint2 pk; pk.x = (hx << 16) | lx; pk.y = (hy << 16) | ly;
        *(uint2*)&zgG[(size_t)node * 128 + 2 * l] = pk;   // coalesced 512B/node
    }
    __syncthreads();   // barrier drains vmcnt -> all zg stores visible block-wide

    // ---- MFMA: A-frags re-read from zg (L2-hot, each byte once), W streamed via wS ----
    f32x4 acc[8] = {};
    const int rowa = wv * 16 + la;
    const bool act = (wv < AW);
    for (int c = 0; c < 4; ++c) {
        uint4 u0 = {}, u1 = {};
        if (act) {
            const uint4* zp = (const uint4*)&zgG[(size_t)rowa * 128 + c * 32 + kg * 8];
            u0 = zp[0]; u1 = zp[1];
        }
        int e0 = (t & 511) * 8; int n = e0 >> 5, kk = e0 & 31;
        const bf16x8* gsrc = (const bf16x8*)((t < 512 ? WH : WL) + n * 128 + c * 32 + kk);
        bf16x8 wreg = *gsrc;                 // global load overlaps barrier below
        __syncthreads();                      // prev chunk's MFMA reads done
        *(bf16x8*)&wS[t >> 9][e0 ^ (((n >> 1) & 3) << 3)] = wreg;
        __syncthreads();
        if (act) {
            union { unsigned u[4]; bf16x8 v; } AH, AL;
            AH.u[0] = (u0.x >> 16) | (u0.y & 0xffff0000u); AL.u[0] = (u0.x & 0xffffu) | (u0.y << 16);
            AH.u[1] = (u0.z >> 16) | (u0.w & 0xffff0000u); AL.u[1] = (u0.z & 0xffffu) | (u0.w << 16);
            AH.u[2] = (u1.x >> 16) | (u1.y & 0xffff0000u); AL.u[2] = (u1.x & 0xffffu) | (u1.y << 16);
            AH.u[3] = (u1.z >> 16) | (u1.w & 0xffff0000u); AL.u[3] = (u1.z & 0xffffu) | (u1.w << 16);
#pragma unroll
            for (int gi = 0; gi < 8; ++gi) {
                int nn = gi * 16 + la;
                int bi = (nn * 32 + kg * 8) ^ (((nn >> 1) & 3) << 3);
                bf16x8 bh = *(const bf16x8*)&wS[0][bi];
                bf16x8 bl = *(const bf16x8*)&wS[1][bi];
                acc[gi] = __builtin_amdgcn_mfma_f32_16x16x32_bf16(AH.v, bh, acc[gi], 0, 0, 0);
                acc[gi] = __builtin_amdgcn_mfma_f32_16x16x32_bf16(AH.v, bl, acc[gi], 0, 0, 0);
                acc[gi] = __builtin_amdgcn_mfma_f32_16x16x32_bf16(AL.v, bh, acc[gi], 0, 0, 0);
            }
        }
    }
    __syncthreads();   // wS free -> reuse for BN partials

    // ---- bias + BN partial stats (partials in wS, NOT aliasing h) ----
    float* partS = (float*)&wS[0][0];   // 2048 floats
    float* partQ = (float*)&wS[1][0];
    if (act) {
#pragma unroll
        for (int gi = 0; gi < 8; ++gi) {
            int col = gi * 16 + la;
            float bv = bgL[col];
            float s = 0.f, q = 0.f;
#pragma unroll
            for (int r = 0; r < 4; ++r) {
                float o = acc[gi][r] + bv;
                acc[gi][r] = o;
                s += o; q += o * o;
            }
            s += __shfl_xor(s, 16); s += __shfl_xor(s, 32);
            q += __shfl_xor(q, 16); q += __shfl_xor(q, 32);
            if (kg == 0) { partS[wv * 128 + col] = s; partQ[wv * 128 + col] = q; }
        }
    }
    __syncthreads();
    if (t < 128) {
        float s = 0.f, q = 0.f;
#pragma unroll
        for (int i = 0; i < AW; ++i) { s += partS[i * 128 + t]; q += partQ[i * 128 + t]; }
        atomicAdd(&bnstL[t], s);
        atomicAdd(&bnstL[128 + t], q);
    }
    grid.sync();
    if (t < 128) {
        float s = __hip_atomic_load(&bnstL[t], __ATOMIC_RELAXED, __HIP_MEMORY_SCOPE_AGENT);
        float q = __hip_atomic_load(&bnstL[128 + t], __ATOMIC_RELAXED, __HIP_MEMORY_SCOPE_AGENT);
        float mu = s * invRows;
        float var = q * invRows - mu * mu;
        float istd = rsqrtf(var + BN_EPS);
        float ga = gamL[t], be = betL[t];
        scsh[t] = ga * istd;
        scsh[128 + t] = be - mu * ga * istd;
    }
    __syncthreads();
    // ---- BN apply + ReLU -> h (h was only read this layer; safe to overwrite now) ----
    if (act) {
#pragma unroll
        for (int gi = 0; gi < 8; ++gi) {
            int col = gi * 16 + la;
            float sc = scsh[col], sh = scsh[128 + col];
#pragma unroll
            for (int r = 0; r < 4; ++r) {
                int row = wv * 16 + kg * 4 + r;
                hF[row * 128 + col] = fmaxf(acc[gi][r] * sc + sh, 0.f);
            }
        }
    }
    __syncthreads();
}

// ---------------- The whole network: one graph per block, h resident in LDS ----------------
__global__ __launch_bounds__(1024, 4) void k_mega(
    const int* __restrict__ x, const int* __restrict__ ei,
    const float* __restrict__ emb,
    const unsigned short* __restrict__ wtHi, const unsigned short* __restrict__ wtLo,
    const float* __restrict__ bg, const float* __restrict__ gam,
    const float* __restrict__ bet, const float* __restrict__ epsArr,
    const float* __restrict__ tw, const float* __restrict__ oW,
    const float* __restrict__ ob, float* __restrict__ bnst,
    unsigned* __restrict__ zg, float* __restrict__ out)
{
    cg::grid_group grid = cg::this_grid();

    __shared__ __align__(16) unsigned char U[131072];      // h f32 [256][128]
    __shared__ __align__(16) unsigned short wS[2][4096];   // W chunk hi/lo; xr/BN-partial alias
    __shared__ unsigned char csr8[4096];
    __shared__ int offl[257];
    __shared__ int curl[256];
    __shared__ int sscan[256];
    __shared__ float score[256];
    __shared__ float scsh[256];
    __shared__ float wlds[128];
    __shared__ float pooled[128];
    __shared__ unsigned char newid[256];
    __shared__ unsigned char perml[128];
    __shared__ unsigned char flg[256];
    __shared__ float invn_s;

    float* hF = (float*)U;
    float2* hF2 = (float2*)U;

    const int g = blockIdx.x;
    const int t = threadIdx.x;
    const int wv = t >> 6, l = t & 63;
    const int nbase = g * NPGC;
    const int* srcg = ei + g * 4096;
    const int* dstg = ei + EE + g * 4096;
    unsigned* zgG = zg + (size_t)g * NPGC * 128;

    // ================= atom encoder =================
    {
        int* xr = (int*)wS;  // 2304 ints
        for (int i = t; i < NPGC * 9; i += 1024) xr[i] = x[nbase * 9 + i];
        __syncthreads();
        int n = t >> 2, cq = (t & 3) << 5;
        f32x4 a8[8] = {};
#pragma unroll
        for (int f = 0; f < 9; ++f) {
            const f32x4* ep = (const f32x4*)&emb[(size_t)((f << 7) + xr[n * 9 + f]) * DD + cq];
#pragma unroll
            for (int q = 0; q < 8; ++q) a8[q] += ep[q];
        }
        f32x4* hq = (f32x4*)&hF[n * DD + cq];
#pragma unroll
        for (int q = 0; q < 8; ++q) hq[q] = a8[q];
    }

    // ================= CSR1 (block-local) =================
    for (int i = t; i < 256; i += 1024) curl[i] = 0;
    __syncthreads();
    for (int i = t; i < 4096; i += 1024) atomicAdd(&curl[dstg[i] - nbase], 1);
    __syncthreads();
    if (t < 256) sscan[t] = curl[t];
    __syncthreads();
    for (int d = 1; d < 256; d <<= 1) {
        int v = (t < 256 && t >= d) ? sscan[t - d] : 0;
        __syncthreads();
        if (t < 256) sscan[t] += v;
        __syncthreads();
    }
    if (t < 256) offl[t] = sscan[t] - curl[t];
    if (t == 0) offl[256] = 4096;
    for (int i = t; i < 256; i += 1024) curl[i] = 0;
    __syncthreads();
    for (int i = t; i < 4096; i += 1024) {
        int d = dstg[i] - nbase;
        int slot = offl[d] + atomicAdd(&curl[d], 1);
        csr8[slot] = (unsigned char)(srcg[i] - nbase);
    }
    __syncthreads();

    // ================= phase-1: 3 GIN layers on 256 nodes =================
    for (int L = 0; L < 3; ++L) {
        gin_layer<256>(t, zgG, hF, wS, offl, csr8,
                       wtHi + L * 16384, wtLo + L * 16384,
                       bg + L * DD, gam + L * DD, bet + L * DD, epsArr[L],
                       bnst + L * 256, INV_N1, scsh, grid);
    }

    // ================= score / top-k / gate (block-local) =================
    if (t < DD) wlds[t] = tw[t];
    __syncthreads();
    if (t < DD) score[t] = wlds[t] * wlds[t];
    __syncthreads();
    for (int d = 64; d > 0; d >>= 1) {
        if (t < d) score[t] += score[t + d];
        __syncthreads();
    }
    if (t == 0) invn_s = rsqrtf(score[0]);
    __syncthreads();
    {
        float wx = wlds[l * 2], wy = wlds[l * 2 + 1];
        for (int i = 0; i < 16; ++i) {
            int node = wv * 16 + i;
            float2 a = hF2[node * 64 + l];
            float p = a.x * wx + a.y * wy;
            p += __shfl_xor(p, 32); p += __shfl_xor(p, 16); p += __shfl_xor(p, 8);
            p += __shfl_xor(p, 4);  p += __shfl_xor(p, 2);  p += __shfl_xor(p, 1);
            if (l == 0) score[node] = p * invn_s;
        }
    }
    __syncthreads();
    if (t < 256) {
        float v = score[t];
        int rank = 0;
        for (int j = 0; j < 256; ++j) {
            float u = score[j];
            rank += (u > v) || (u == v && j < t);
        }
        int sel = rank < KK ? 1 : 0;
        flg[t] = (unsigned char)sel;
        sscan[t] = sel;
    }
    __syncthreads();
    for (int d = 1; d < 256; d <<= 1) {
        int v = (t < 256 && t >= d) ? sscan[t - d] : 0;
        __syncthreads();
        if (t < 256) sscan[t] += v;
        __syncthreads();
    }
    if (t < 256) {
        if (flg[t]) {
            int m = sscan[t] - 1;
            newid[t] = (unsigned char)m;
            perml[m] = (unsigned char)t;
        } else {
            newid[t] = 0xFF;
        }
    }
    __syncthreads();
    {
        int m = t >> 3, cs = (t & 7) << 4;
        int src = perml[m];
        float tg = tanhf(score[src]);
        f32x4 gv[4];
#pragma unroll
        for (int q = 0; q < 4; ++q) {
            gv[q] = ((const f32x4*)&hF[src * DD + cs])[q];
            gv[q].x *= tg; gv[q].y *= tg; gv[q].z *= tg; gv[q].w *= tg;
        }
        __syncthreads();
#pragma unroll
        for (int q = 0; q < 4; ++q) ((f32x4*)&hF[m * DD + cs])[q] = gv[q];
    }
    __syncthreads();

    // ================= CSR2 (kept edges, block-local) =================
    for (int i = t; i < 256; i += 1024) curl[i] = 0;
    __syncthreads();
    for (int i = t; i < 4096; i += 1024) {
        int sn = newid[srcg[i] - nbase], dn = newid[dstg[i] - nbase];
        if (sn != 255 && dn != 255) atomicAdd(&curl[dn], 1);
    }
    __syncthreads();
    if (t < 256) sscan[t] = curl[t];
    __syncthreads();
    for (int d = 1; d < 256; d <<= 1) {
        int v = (t < 256 && t >= d) ? sscan[t - d] : 0;
        __syncthreads();
        if (t < 256) sscan[t] += v;
        __syncthreads();
    }
    if (t < 256) offl[t] = sscan[t] - curl[t];
    if (t == 0) offl[256] = sscan[255];
    for (int i = t; i < 256; i += 1024) curl[i] = 0;
    __syncthreads();
    for (int i = t; i < 4096; i += 1024) {
        int sn = newid[srcg[i] - nbase], dn = newid[dstg[i] - nbase];
        if (sn != 255 && dn != 255) {
            int slot = offl[dn] + atomicAdd(&curl[dn], 1);
            csr8[slot] = (unsigned char)sn;
        }
    }
    __syncthreads();

    // ================= phase-2: 2 GIN layers on 128 nodes =================
    for (int L = 3; L < 5; ++L) {
        gin_layer<128>(t, zgG, hF, wS, offl, csr8,
                       wtHi + L * 16384, wtLo + L * 16384,
                       bg + L * DD, gam + L * DD, bet + L * DD, epsArr[L],
                       bnst + L * 256, INV_N2, scsh, grid);
    }

    // ================= mean-pool + head + sigmoid =================
    {
        float* partP = (float*)(U + 65536);     // rows 128..255 of hF: dead in phase 2
        int c = t & 127, grp = t >> 7;
        float s = 0.f;
        for (int r = grp * 16; r < grp * 16 + 16; ++r) s += hF[r * DD + c];
        partP[grp * DD + c] = s;
        float* oWl = (float*)(U + 65536 + 8192);
        for (int i = t; i < DD * OUTD; i += 1024) oWl[i] = oW[i];
        __syncthreads();
        if (t < DD) {
            float s2 = 0.f;
#pragma unroll
            for (int i = 0; i < 8; ++i) s2 += partP[i * DD + t];
            pooled[t] = s2 * (1.f / (float)KK);
        }
        __syncthreads();
        if (t < OUTD) {
            float o = ob[t];
            for (int k = 0; k < DD; ++k) o += pooled[k] * oWl[k * OUTD + t];
            out[g * OUTD + t] = 1.f / (1.f + expf(-o));
        }
    }
}

extern "C" void kernel_launch(void* const* d_in, const int* in_sizes, int n_in,
                              void* d_out, int out_size, void* d_ws, size_t ws_size,
                              hipStream_t stream) {
    const int*   x        = (const int*)d_in[0];
    const int*   ei       = (const int*)d_in[1];
    const float* atom_emb = (const float*)d_in[4];
    const float* convW    = (const float*)d_in[6];
    const float* convb    = (const float*)d_in[7];
    const float* gam      = (const float*)d_in[8];
    const float* bet      = (const float*)d_in[9];
    const float* eps      = (const float*)d_in[10];
    const float* tw       = (const float*)d_in[11];
    const float* oW       = (const float*)d_in[12];
    const float* ob       = (const float*)d_in[13];
    float* outp = (float*)d_out;

    char* p = (char*)d_ws;
    unsigned* zg = (unsigned*)p;               p += (size_t)NN * DD * 4;   // 32MB staging
    float* bnst = (float*)p;                   p += (size_t)5 * 256 * 4;
    unsigned short* wtHi = (unsigned short*)p; p += (size_t)5 * DD * DD * 2;
    unsigned short* wtLo = (unsigned short*)p; p += (size_t)5 * DD * DD * 2;
    if ((size_t)(p - (char*)d_ws) > ws_size) return;

    hipMemsetAsync(bnst, 0, (size_t)5 * 256 * 4, stream);
    k_prepw<<<640, 128, 0, stream>>>(convW, wtHi, wtLo);

    void* args[] = {
        (void*)&x, (void*)&ei, (void*)&atom_emb, (void*)&wtHi, (void*)&wtLo,
        (void*)&convb, (void*)&gam, (void*)&bet, (void*)&eps, (void*)&tw,
        (void*)&oW, (void*)&ob, (void*)&bnst, (void*)&zg, (void*)&outp
    };
    hipLaunchCooperativeKernel((void*)k_mega, dim3(BB), dim3(1024), args, 0, stream);
}

// Round 8
// 324.138 us; speedup vs baseline: 1.1772x; 1.1772x over previous
//
#include <hip/hip_runtime.h>
#include <math.h>

#define NN   65536
#define BB   256
#define NPGC 256
#define EE   1048576
#define DD   128
#define KK   128
#define NT2  32768
#define OUTD 12
#define BN_EPS 1e-5f
#define INV_N1 (1.f / 65536.f)
#define INV_N2 (1.f / 32768.f)

typedef __attribute__((ext_vector_type(8))) short bf16x8;
typedef __attribute__((ext_vector_type(4))) float f32x4;

__device__ __forceinline__ unsigned short bf16_rne(float v) {
    unsigned u = __float_as_uint(v);
    unsigned r = u + 0x7FFFu + ((u >> 16) & 1u);
    return (unsigned short)(r >> 16);
}

// ---------------- W prep: transpose + split f32 -> bf16 hi/lo, [layer][n][k] ----------------
__global__ void k_prepw(const float* __restrict__ Wg, unsigned short* __restrict__ wtHi,
                        unsigned short* __restrict__ wtLo) {
    int b = blockIdx.x;            // 0..639
    int l = b >> 7, n = b & 127;
    int k = threadIdx.x;           // 128
    float v = Wg[l * 16384 + k * 128 + n];
    unsigned short hb = bf16_rne(v);
    float hf = __uint_as_float((unsigned)hb << 16);
    unsigned short lb = bf16_rne(v - hf);
    wtHi[l * 16384 + n * 128 + k] = hb;
    wtLo[l * 16384 + n * 128 + k] = lb;
}

// 256-element inclusive scan, 2 barriers (wave shuffle within 4 waves of t<256)
__device__ __forceinline__ void scan256(int t, const int* in, int* out, int* wtot) {
    int lane = t & 63, w = t >> 6;
    int v = (t < 256) ? in[t] : 0;
    int sv = v;
#pragma unroll
    for (int d = 1; d < 64; d <<= 1) {
        int u = __shfl_up(sv, d);
        if (lane >= d) sv += u;
    }
    if (t < 256 && lane == 63) wtot[w] = sv;
    __syncthreads();
    if (t < 256) {
        int off = 0;
        for (int i = 0; i < w; ++i) off += wtot[i];
        out[t] = sv + off;   // inclusive
    }
    __syncthreads();
}

// ---------------- The whole network: one graph per block, h resident in LDS ----------------
__global__ __launch_bounds__(1024) void k_mega(
    const int* __restrict__ x, const int* __restrict__ ei,
    const float* __restrict__ emb,
    const unsigned short* __restrict__ wtHi, const unsigned short* __restrict__ wtLo,
    const float* __restrict__ bg, const float* __restrict__ gam,
    const float* __restrict__ bet, const float* __restrict__ epsArr,
    const float* __restrict__ tw, const float* __restrict__ oW,
    const float* __restrict__ ob, float* __restrict__ bnst,
    float* __restrict__ out)
{
    __shared__ __align__(16) unsigned char U[131072];      // h f32 [256][128] OR bf16 A-tiles
    __shared__ __align__(16) unsigned short wS[2][4096];   // W chunk hi/lo; xr alias early
    __shared__ unsigned char csr8[4096];
    __shared__ int offl[257];
    __shared__ int curl[256];
    __shared__ int sscan[256];
    __shared__ int wtot[4];
    __shared__ float score[256];
    __shared__ float scsh[256];
    __shared__ float wlds[128];
    __shared__ float pooled[128];
    __shared__ unsigned char newid[256];
    __shared__ unsigned char perml[128];
    __shared__ unsigned char flg[256];
    __shared__ float invn_s;

    float* hF = (float*)U;
    float2* hF2 = (float2*)U;
    unsigned short* aHi = (unsigned short*)U;
    unsigned short* aLo = (unsigned short*)(U + 65536);
    unsigned* bcnt = (unsigned*)(bnst + 5 * 256);

    const int g = blockIdx.x;
    const int t = threadIdx.x;
    const int wv = t >> 6, l = t & 63;
    const int la = l & 15, kg = l >> 4;
    const int nbase = g * NPGC;
    const int* srcg = ei + g * 4096;
    const int* dstg = ei + EE + g * 4096;

    // ================= atom encoder =================
    {
        int* xr = (int*)wS;  // 2304 ints
        for (int i = t; i < NPGC * 9; i += 1024) xr[i] = x[nbase * 9 + i];
        __syncthreads();
        int n = t >> 2, cq = (t & 3) << 5;
        f32x4 a8[8] = {};
#pragma unroll
        for (int f = 0; f < 9; ++f) {
            const f32x4* ep = (const f32x4*)&emb[(size_t)((f << 7) + xr[n * 9 + f]) * DD + cq];
#pragma unroll
            for (int q = 0; q < 8; ++q) a8[q] += ep[q];
        }
        f32x4* hq = (f32x4*)&hF[n * DD + cq];
#pragma unroll
        for (int q = 0; q < 8; ++q) hq[q] = a8[q];
    }

    // ================= CSR1 (block-local) =================
    for (int i = t; i < 256; i += 1024) curl[i] = 0;
    __syncthreads();
    for (int i = t; i < 4096; i += 1024) atomicAdd(&curl[dstg[i] - nbase], 1);
    __syncthreads();
    scan256(t, curl, sscan, wtot);
    if (t < 256) offl[t] = sscan[t] - curl[t];
    if (t == 0) offl[256] = 4096;
    for (int i = t; i < 256; i += 1024) curl[i] = 0;
    __syncthreads();
    for (int i = t; i < 4096; i += 1024) {
        int d = dstg[i] - nbase;
        int slot = offl[d] + atomicAdd(&curl[d], 1);
        csr8[slot] = (unsigned char)(srcg[i] - nbase);
    }
    __syncthreads();

    // ================= phase-1: 3 GIN layers on 256 nodes =================
    for (int L = 0; L < 3; ++L) {
        const float opEps = 1.f + epsArr[L];
        float agx[16], agy[16];
#pragma unroll
        for (int i = 0; i < 16; ++i) {
            int node = wv * 16 + i;
            int st = offl[node], en = offl[node + 1];
            float2 a = hF2[node * 64 + l];
            float ax = a.x * opEps, ay = a.y * opEps;
            int j = st;
            for (; j + 3 < en; j += 4) {
                int n0 = csr8[j], n1 = csr8[j + 1], n2 = csr8[j + 2], n3 = csr8[j + 3];
                float2 v0 = hF2[n0 * 64 + l];
                float2 v1 = hF2[n1 * 64 + l];
                float2 v2 = hF2[n2 * 64 + l];
                float2 v3 = hF2[n3 * 64 + l];
                ax += v0.x + v1.x + v2.x + v3.x;
                ay += v0.y + v1.y + v2.y + v3.y;
            }
            for (; j < en; ++j) {
                float2 v = hF2[csr8[j] * 64 + l];
                ax += v.x; ay += v.y;
            }
            agx[i] = ax; agy[i] = ay;
        }
        __syncthreads();
#pragma unroll
        for (int i = 0; i < 16; ++i) {
            int node = wv * 16 + i;
            int idx = (node * DD + l * 2) ^ ((node & 7) << 3);
            unsigned short hx = bf16_rne(agx[i]);
            unsigned short hy = bf16_rne(agy[i]);
            float rx = agx[i] - __uint_as_float((unsigned)hx << 16);
            float ry = agy[i] - __uint_as_float((unsigned)hy << 16);
            *(unsigned*)&aHi[idx] = (unsigned)hx | ((unsigned)hy << 16);
            *(unsigned*)&aLo[idx] = (unsigned)bf16_rne(rx) | ((unsigned)bf16_rne(ry) << 16);
        }
        const unsigned short* WH = wtHi + L * 16384;
        const unsigned short* WL = wtLo + L * 16384;
        f32x4 acc[8] = {};
        const int rowa = wv * 16 + la;
        const int aXor = (rowa & 7) << 3;
        int e0 = (t & 511) * 8;
        int wn = e0 >> 5, wk = e0 & 31;
        int wdst = e0 ^ (((wn >> 1) & 3) << 3);
        const unsigned short* wbase = (t < 512 ? WH : WL) + wn * 128 + wk;
        bf16x8 wreg = *(const bf16x8*)wbase;
        for (int c = 0; c < 4; ++c) {
            __syncthreads();                       // prev chunk's wS reads done; A-writes visible
            *(bf16x8*)&wS[t >> 9][wdst] = wreg;
            __syncthreads();                       // wS ready
            if (c < 3) wreg = *(const bf16x8*)(wbase + (c + 1) * 32);   // hides under MFMA
            int ai = (rowa * DD + c * 32 + kg * 8) ^ aXor;
            bf16x8 ah = *(const bf16x8*)&aHi[ai];
            bf16x8 al = *(const bf16x8*)&aLo[ai];
#pragma unroll
            for (int gi = 0; gi < 8; ++gi) {
                int nn = gi * 16 + la;
                int bi = (nn * 32 + kg * 8) ^ (((nn >> 1) & 3) << 3);
                bf16x8 bh = *(const bf16x8*)&wS[0][bi];
                bf16x8 bl = *(const bf16x8*)&wS[1][bi];
                acc[gi] = __builtin_amdgcn_mfma_f32_16x16x32_bf16(ah, bh, acc[gi], 0, 0, 0);
                acc[gi] = __builtin_amdgcn_mfma_f32_16x16x32_bf16(ah, bl, acc[gi], 0, 0, 0);
                acc[gi] = __builtin_amdgcn_mfma_f32_16x16x32_bf16(al, bh, acc[gi], 0, 0, 0);
            }
        }
        __syncthreads();
        float* partS = (float*)U;
        float* partQ = (float*)(U + 8192);
#pragma unroll
        for (int gi = 0; gi < 8; ++gi) {
            int col = gi * 16 + la;
            float bv = bg[L * DD + col];
            float s = 0.f, q = 0.f;
#pragma unroll
            for (int r = 0; r < 4; ++r) {
                float o = acc[gi][r] + bv;
                acc[gi][r] = o;
                s += o; q += o * o;
            }
            s += __shfl_xor(s, 16); s += __shfl_xor(s, 32);
            q += __shfl_xor(q, 16); q += __shfl_xor(q, 32);
            if (kg == 0) { partS[wv * DD + col] = s; partQ[wv * DD + col] = q; }
        }
        __syncthreads();
        if (t < DD) {
            float s = 0.f, q = 0.f;
#pragma unroll
            for (int i = 0; i < 16; ++i) { s += partS[i * DD + t]; q += partQ[i * DD + t]; }
            atomicAdd(&bnst[L * 256 + t], s);
            atomicAdd(&bnst[L * 256 + DD + t], q);
        }
        // ---- hand-rolled grid barrier (monotonic counter, agent scope) ----
        __syncthreads();
        if (t == 0) {
            __threadfence();
            atomicAdd(bcnt, 1u);
            unsigned tgt = 256u * (unsigned)(L + 1);
            while (__hip_atomic_load(bcnt, __ATOMIC_RELAXED, __HIP_MEMORY_SCOPE_AGENT) < tgt)
                __builtin_amdgcn_s_sleep(2);
            __threadfence();
        }
        __syncthreads();
        if (t < DD) {
            float s = __hip_atomic_load(&bnst[L * 256 + t], __ATOMIC_RELAXED, __HIP_MEMORY_SCOPE_AGENT);
            float q = __hip_atomic_load(&bnst[L * 256 + DD + t], __ATOMIC_RELAXED, __HIP_MEMORY_SCOPE_AGENT);
            float mu = s * INV_N1;
            float var = q * INV_N1 - mu * mu;
            float istd = rsqrtf(var + BN_EPS);
            float ga = gam[L * DD + t], be = bet[L * DD + t];
            scsh[t] = ga * istd;
            scsh[DD + t] = be - mu * ga * istd;
        }
        __syncthreads();
#pragma unroll
        for (int gi = 0; gi < 8; ++gi) {
            int col = gi * 16 + la;
            float sc = scsh[col], sh = scsh[DD + col];
#pragma unroll
            for (int r = 0; r < 4; ++r) {
                int row = wv * 16 + kg * 4 + r;
                hF[row * DD + col] = fmaxf(acc[gi][r] * sc + sh, 0.f);
            }
        }
        __syncthreads();
    }

    // ================= score / top-k / gate (block-local) =================
    if (t < DD) wlds[t] = tw[t];
    __syncthreads();
    if (t < 64) {
        float s = wlds[t] * wlds[t] + wlds[t + 64] * wlds[t + 64];
#pragma unroll
        for (int d = 32; d > 0; d >>= 1) s += __shfl_down(s, d);
        if (t == 0) invn_s = rsqrtf(s);
    }
    __syncthreads();
    {
        float wx = wlds[l * 2], wy = wlds[l * 2 + 1];
        for (int i = 0; i < 16; ++i) {
            int node = wv * 16 + i;
            float2 a = hF2[node * 64 + l];
            float p = a.x * wx + a.y * wy;
            p += __shfl_xor(p, 32); p += __shfl_xor(p, 16); p += __shfl_xor(p, 8);
            p += __shfl_xor(p, 4);  p += __shfl_xor(p, 2);  p += __shfl_xor(p, 1);
            if (l == 0) score[node] = p * invn_s;
        }
    }
    __syncthreads();
    if (t < 256) {
        float v = score[t];
        int rank = 0;
        for (int j = 0; j < 256; ++j) {
            float u = score[j];
            rank += (u > v) || (u == v && j < t);
        }
        int sel = rank < KK ? 1 : 0;
        flg[t] = (unsigned char)sel;
        sscan[t] = sel;
    }
    __syncthreads();
    scan256(t, sscan, sscan, wtot);
    if (t < 256) {
        if (flg[t]) {
            int m = sscan[t] - 1;
            newid[t] = (unsigned char)m;
            perml[m] = (unsigned char)t;
        } else {
            newid[t] = 0xFF;
        }
    }
    __syncthreads();
    {
        int m = t >> 3, cs = (t & 7) << 4;
        int src = perml[m];
        float tg = tanhf(score[src]);
        f32x4 gv[4];
#pragma unroll
        for (int q = 0; q < 4; ++q) {
            gv[q] = ((const f32x4*)&hF[src * DD + cs])[q];
            gv[q].x *= tg; gv[q].y *= tg; gv[q].z *= tg; gv[q].w *= tg;
        }
        __syncthreads();
#pragma unroll
        for (int q = 0; q < 4; ++q) ((f32x4*)&hF[m * DD + cs])[q] = gv[q];
    }
    __syncthreads();

    // ================= CSR2 (kept edges, block-local) =================
    for (int i = t; i < 256; i += 1024) curl[i] = 0;
    __syncthreads();
    for (int i = t; i < 4096; i += 1024) {
        int sn = newid[srcg[i] - nbase], dn = newid[dstg[i] - nbase];
        if (sn != 255 && dn != 255) atomicAdd(&curl[dn], 1);
    }
    __syncthreads();
    scan256(t, curl, sscan, wtot);
    if (t < 256) offl[t] = sscan[t] - curl[t];
    for (int i = t; i < 256; i += 1024) curl[i] = 0;
    __syncthreads();
    for (int i = t; i < 4096; i += 1024) {
        int sn = newid[srcg[i] - nbase], dn = newid[dstg[i] - nbase];
        if (sn != 255 && dn != 255) {
            int slot = offl[dn] + atomicAdd(&curl[dn], 1);
            csr8[slot] = (unsigned char)sn;
        }
    }
    __syncthreads();

    // ================= phase-2: 2 GIN layers on 128 nodes =================
    unsigned short* aHi2 = (unsigned short*)(U + 65536);
    unsigned short* aLo2 = (unsigned short*)(U + 65536 + 32768);
    for (int L = 3; L < 5; ++L) {
        const float opEps = 1.f + epsArr[L];
        float agx[8], agy[8];
#pragma unroll
        for (int i = 0; i < 8; ++i) {
            int node = wv * 8 + i;
            int st = offl[node], en = offl[node + 1];
            float2 a = hF2[node * 64 + l];
            float ax = a.x * opEps, ay = a.y * opEps;
            int j = st;
            for (; j + 3 < en; j += 4) {
                int n0 = csr8[j], n1 = csr8[j + 1], n2 = csr8[j + 2], n3 = csr8[j + 3];
                float2 v0 = hF2[n0 * 64 + l];
                float2 v1 = hF2[n1 * 64 + l];
                float2 v2 = hF2[n2 * 64 + l];
                float2 v3 = hF2[n3 * 64 + l];
                ax += v0.x + v1.x + v2.x + v3.x;
                ay += v0.y + v1.y + v2.y + v3.y;
            }
            for (; j < en; ++j) {
                float2 v = hF2[csr8[j] * 64 + l];
                ax += v.x; ay += v.y;
            }
            agx[i] = ax; agy[i] = ay;
        }
        __syncthreads();
#pragma unroll
        for (int i = 0; i < 8; ++i) {
            int node = wv * 8 + i;
            int idx = (node * DD + l * 2) ^ ((node & 7) << 3);
            unsigned short hx = bf16_rne(agx[i]);
            unsigned short hy = bf16_rne(agy[i]);
            float rx = agx[i] - __uint_as_float((unsigned)hx << 16);
            float ry = agy[i] - __uint_as_float((unsigned)hy << 16);
            *(unsigned*)&aHi2[idx] = (unsigned)hx | ((unsigned)hy << 16);
            *(unsigned*)&aLo2[idx] = (unsigned)bf16_rne(rx) | ((unsigned)bf16_rne(ry) << 16);
        }
        const unsigned short* WH = wtHi + L * 16384;
        const unsigned short* WL = wtLo + L * 16384;
        f32x4 acc[8] = {};
        const int rowa = wv * 16 + la;  // valid for wv < 8
        const int aXor = (rowa & 7) << 3;
        int e0 = (t & 511) * 8;
        int wn = e0 >> 5, wk = e0 & 31;
        int wdst = e0 ^ (((wn >> 1) & 3) << 3);
        const unsigned short* wbase = (t < 512 ? WH : WL) + wn * 128 + wk;
        bf16x8 wreg = *(const bf16x8*)wbase;
        for (int c = 0; c < 4; ++c) {
            __syncthreads();
            *(bf16x8*)&wS[t >> 9][wdst] = wreg;
            __syncthreads();
            if (c < 3) wreg = *(const bf16x8*)(wbase + (c + 1) * 32);
            if (wv < 8) {
                int ai = (rowa * DD + c * 32 + kg * 8) ^ aXor;
                bf16x8 ah = *(const bf16x8*)&aHi2[ai];
                bf16x8 al = *(const bf16x8*)&aLo2[ai];
#pragma unroll
                for (int gi = 0; gi < 8; ++gi) {
                    int nn = gi * 16 + la;
                    int bi = (nn * 32 + kg * 8) ^ (((nn >> 1) & 3) << 3);
                    bf16x8 bh = *(const bf16x8*)&wS[0][bi];
                    bf16x8 bl = *(const bf16x8*)&wS[1][bi];
                    acc[gi] = __builtin_amdgcn_mfma_f32_16x16x32_bf16(ah, bh, acc[gi], 0, 0, 0);
                    acc[gi] = __builtin_amdgcn_mfma_f32_16x16x32_bf16(ah, bl, acc[gi], 0, 0, 0);
                    acc[gi] = __builtin_amdgcn_mfma_f32_16x16x32_bf16(al, bh, acc[gi], 0, 0, 0);
                }
            }
        }
        __syncthreads();
        float* partS = (float*)(U + 65536);
        float* partQ = (float*)(U + 65536 + 4096);
        if (wv < 8) {
#pragma unroll
            for (int gi = 0; gi < 8; ++gi) {
                int col = gi * 16 + la;
                float bv = bg[L * DD + col];
                float s = 0.f, q = 0.f;
#pragma unroll
                for (int r = 0; r < 4; ++r) {
                    float o = acc[gi][r] + bv;
                    acc[gi][r] = o;
                    s += o; q += o * o;
                }
                s += __shfl_xor(s, 16); s += __shfl_xor(s, 32);
                q += __shfl_xor(q, 16); q += __shfl_xor(q, 32);
                if (kg == 0) { partS[wv * 128 + col] = s; partQ[wv * 128 + col] = q; }
            }
        }
        __syncthreads();
        if (t < DD) {
            float s = 0.f, q = 0.f;
#pragma unroll
            for (int i = 0; i < 8; ++i) { s += partS[i * 128 + t]; q += partQ[i * 128 + t]; }
            atomicAdd(&bnst[L * 256 + t], s);
            atomicAdd(&bnst[L * 256 + DD + t], q);
        }
        __syncthreads();
        if (t == 0) {
            __threadfence();
            atomicAdd(bcnt, 1u);
            unsigned tgt = 256u * (unsigned)(L + 1);
            while (__hip_atomic_load(bcnt, __ATOMIC_RELAXED, __HIP_MEMORY_SCOPE_AGENT) < tgt)
                __builtin_amdgcn_s_sleep(2);
            __threadfence();
        }
        __syncthreads();
        if (t < DD) {
            float s = __hip_atomic_load(&bnst[L * 256 + t], __ATOMIC_RELAXED, __HIP_MEMORY_SCOPE_AGENT);
            float q = __hip_atomic_load(&bnst[L * 256 + DD + t], __ATOMIC_RELAXED, __HIP_MEMORY_SCOPE_AGENT);
            float mu = s * INV_N2;
            float var = q * INV_N2 - mu * mu;
            float istd = rsqrtf(var + BN_EPS);
            float ga = gam[L * DD + t], be = bet[L * DD + t];
            scsh[t] = ga * istd;
            scsh[DD + t] = be - mu * ga * istd;
        }
        __syncthreads();
        if (wv < 8) {
#pragma unroll
            for (int gi = 0; gi < 8; ++gi) {
                int col = gi * 16 + la;
                float sc = scsh[col], sh = scsh[DD + col];
#pragma unroll
                for (int r = 0; r < 4; ++r) {
                    int row = wv * 16 + kg * 4 + r;
                    hF[row * DD + col] = fmaxf(acc[gi][r] * sc + sh, 0.f);
                }
            }
        }
        __syncthreads();
    }

    // ================= mean-pool + head + sigmoid =================
    {
        float* partP = (float*)(U + 65536);     // rows 128..255 of hF: dead in phase 2
        int c = t & 127, grp = t >> 7;
        float s = 0.f;
        for (int r = grp * 16; r < grp * 16 + 16; ++r) s += hF[r * DD + c];
        partP[grp * DD + c] = s;
        float* oWl = (float*)(U + 65536 + 8192);
        for (int i = t; i < DD * OUTD; i += 1024) oWl[i] = oW[i];
        __syncthreads();
        if (t < DD) {
            float s2 = 0.f;
#pragma unroll
            for (int i = 0; i < 8; ++i) s2 += partP[i * DD + t];
            pooled[t] = s2 * (1.f / (float)KK);
        }
        __syncthreads();
        if (t < OUTD) {
            float o = ob[t];
            for (int k = 0; k < DD; ++k) o += pooled[k] * oWl[k * OUTD + t];
            out[g * OUTD + t] = 1.f / (1.f + expf(-o));
        }
    }
}

extern "C" void kernel_launch(void* const* d_in, const int* in_sizes, int n_in,
                              void* d_out, int out_size, void* d_ws, size_t ws_size,
                              hipStream_t stream) {
    const int*   x        = (const int*)d_in[0];
    const int*   ei       = (const int*)d_in[1];
    const float* atom_emb = (const float*)d_in[4];
    const float* convW    = (const float*)d_in[6];
    const float* convb    = (const float*)d_in[7];
    const float* gam      = (const float*)d_in[8];
    const float* bet      = (const float*)d_in[9];
    const float* eps      = (const float*)d_in[10];
    const float* tw       = (const float*)d_in[11];
    const float* oW       = (const float*)d_in[12];
    const float* ob       = (const float*)d_in[13];
    float* outp = (float*)d_out;

    char* p = (char*)d_ws;
    float* bnst = (float*)p;                   p += (size_t)5 * 256 * 4 + 16;  // + barrier counter
    unsigned short* wtHi = (unsigned short*)p; p += (size_t)5 * DD * DD * 2;
    unsigned short* wtLo = (unsigned short*)p; p += (size_t)5 * DD * DD * 2;
    if ((size_t)(p - (char*)d_ws) > ws_size) return;

    hipMemsetAsync(bnst, 0, (size_t)5 * 256 * 4 + 16, stream);
    k_prepw<<<640, 128, 0, stream>>>(convW, wtHi, wtLo);

    void* args[] = {
        (void*)&x, (void*)&ei, (void*)&atom_emb, (void*)&wtHi, (void*)&wtLo,
        (void*)&convb, (void*)&gam, (void*)&bet, (void*)&eps, (void*)&tw,
        (void*)&oW, (void*)&ob, (void*)&bnst, (void*)&outp
    };
    hipLaunchCooperativeKernel((void*)k_mega, dim3(BB), dim3(1024), args, 0, stream);
}